// Round 1
// baseline (883.007 us; speedup 1.0000x reference)
//
#include <hip/hip_runtime.h>
#include <stdint.h>

// Problem dims
#define NB  256
#define NT  100
#define NIN 128
#define NH  1024
#define NOUT 35

// d_out float offsets
#define O_SPK2 26214400ull
#define O_SPK3 52428800ull
#define O_SPK4 78643200ull
#define O_MEM4 79539200ull

// d_ws byte offsets (unchanged layout; total usage <= previous session's)
#define WS_XT   0ull          // 25600*128*4 = 13107200
#define WS_Q1T  13107200ull   // 128*1024*4  = 524288
#define WS_K2T  13631488ull   // 1048576
#define WS_K3T  14680064ull   // 1048576
#define WS_K4T  15728640ull   // 1024*48 = 49152 (padded stride 48)
#define WS_RS2  15777792ull   // 4096
#define WS_RS3  15781888ull   // 4096
#define WS_RS4  15785984ull   // 140

// scale = (w_max - w_min)/15 computed in python fp64 then cast to fp32
#define S2C ((float)((1.0 - 0.001) / 15.0))
#define S1C ((float)(1.0 / 15.0))

// ------------------------------------------------------------------
// K1: quantize weights -> transposed i8 index matrices + q1T fp32 + xt
// ------------------------------------------------------------------
__global__ void k_prep(const float* __restrict__ x, const float* __restrict__ w1,
                       const float* __restrict__ w2, const float* __restrict__ w3,
                       const float* __restrict__ w4, uint8_t* __restrict__ ws)
{
  long long id = (long long)blockIdx.x * 256 + threadIdx.x;
  if (id < 1048576) {                       // k2T[i*1024+j] = k(w2[j][i])
    int i = (int)(id >> 10), j = (int)(id & 1023);
    float wv = w2[(size_t)j * 1024 + i];
    float wc = fminf(fmaxf(wv, 0.001f), 1.0f);
    ws[WS_K2T + id] = (uint8_t)(int)rintf((wc - 0.001f) / S2C);
    return;
  }
  id -= 1048576;
  if (id < 1048576) {                       // k3T
    int i = (int)(id >> 10), j = (int)(id & 1023);
    float wv = w3[(size_t)j * 1024 + i];
    float wc = fminf(fmaxf(wv, 0.001f), 1.0f);
    ws[WS_K3T + id] = (uint8_t)(int)rintf((wc - 0.001f) / S2C);
    return;
  }
  id -= 1048576;
  if (id < 49152) {                         // k4T stride 48, pad j>=35 with 0
    int i = (int)(id / 48), j = (int)(id % 48);
    uint8_t v = 0;
    if (j < NOUT) {
      float wv = w4[(size_t)j * 1024 + i];
      float wc = fminf(fmaxf(wv, 0.001f), 1.0f);
      v = (uint8_t)(int)rintf((wc - 0.001f) / S2C);
    }
    ws[WS_K4T + id] = v;
    return;
  }
  id -= 49152;
  if (id < 131072) {                        // q1T[i*1024+j] = fake_quant(w1[j][i]) fp32
    int i = (int)(id >> 10), j = (int)(id & 1023);
    float wv = w1[(size_t)j * 128 + i];
    float wc = fminf(fmaxf(wv, -0.5f), 0.5f);
    float q = rintf((wc + 0.5f) / S1C) * S1C - 0.5f;
    ((float*)(ws + WS_Q1T))[id] = q;
    return;
  }
  id -= 131072;
  if (id < 3276800) {                       // xt[(t*256+b)*128+i] = x[b][t][i]/15
    int row = (int)(id >> 7), i = (int)(id & 127);
    int tt = row >> 8, bb = row & 255;
    ((float*)(ws + WS_XT))[id] = x[((size_t)bb * NT + tt) * NIN + i] / 15.0f;
  }
}

// ------------------------------------------------------------------
// K2: integer row-sums of k-indices (for complement-mode gathers)
// ------------------------------------------------------------------
__global__ void k_rowsum(const float* __restrict__ w2, const float* __restrict__ w3,
                         const float* __restrict__ w4, uint8_t* __restrict__ ws)
{
  int bid = blockIdx.x, tid = threadIdx.x;
  const float* W;
  uint32_t* o;
  if (bid < 1024)      { W = w2 + (size_t)bid * 1024;          o = (uint32_t*)(ws + WS_RS2) + bid; }
  else if (bid < 2048) { W = w3 + (size_t)(bid - 1024) * 1024; o = (uint32_t*)(ws + WS_RS3) + (bid - 1024); }
  else                 { W = w4 + (size_t)(bid - 2048) * 1024; o = (uint32_t*)(ws + WS_RS4) + (bid - 2048); }
  uint32_t s = 0;
  for (int i = tid; i < 1024; i += 256) {
    float wc = fminf(fmaxf(W[i], 0.001f), 1.0f);
    s += (uint32_t)(int)rintf((wc - 0.001f) / S2C);
  }
  #pragma unroll
  for (int off = 32; off; off >>= 1) s += (uint32_t)__shfl_down((int)s, off);
  __shared__ uint32_t red[4];
  if ((tid & 63) == 0) red[tid >> 6] = s;
  __syncthreads();
  if (tid == 0) *o = red[0] + red[1] + red[2] + red[3];
}

// ------------------------------------------------------------------
// K3 (new): fused layer-1 GEMM + LIF scan. One block per batch elem,
// one thread per hidden neuron j. cur1[b,t,j] accumulated with the
// same ascending-i fmaf chain as the previous k_cur1 (bitwise equal),
// then the t-recursion runs in registers; spk1 written directly.
// xt rows are wave-uniform (b,t fixed) -> scalar/broadcast loads.
// ------------------------------------------------------------------
__global__ __launch_bounds__(1024, 1) void k_spk1(const float* __restrict__ xt,
                                                  const float* __restrict__ q1T,
                                                  float* __restrict__ out)
{
  const int b = blockIdx.x;
  const int j = threadIdx.x;            // neuron 0..1023
  float m1 = 0.f;
  for (int c = 0; c < 4; ++c) {         // 4 chunks of 25 timesteps
    float acc[25];
    #pragma unroll
    for (int tt = 0; tt < 25; ++tt) acc[tt] = 0.f;
    #pragma unroll 2
    for (int ib = 0; ib < 16; ++ib) {   // i-blocks of 8 (i ascending)
      float q[8];
      #pragma unroll
      for (int u = 0; u < 8; ++u) q[u] = q1T[(size_t)(ib * 8 + u) * NH + j];
      #pragma unroll
      for (int tt = 0; tt < 25; ++tt) {
        const float* xr = xt + ((size_t)(c * 25 + tt) * NB + b) * NIN + ib * 8;
        #pragma unroll
        for (int u = 0; u < 8; ++u) acc[tt] = fmaf(xr[u], q[u], acc[tt]);
      }
    }
    #pragma unroll
    for (int tt = 0; tt < 25; ++tt) {   // sequential LIF scan (subtract-reset)
      const int t = c * 25 + tt;
      float rst = m1 > 1.0f ? 1.0f : 0.0f;
      m1 = fmaf(0.9f, m1, acc[tt]) - rst;
      bool sp = (m1 - 1.0f) > 0.0f;
      out[((size_t)t * NB + b) * NH + j] = sp ? 1.0f : 0.0f;
    }
  }
}

// ------------------------------------------------------------------
// K4 (new): persistent per-batch-element SNN loop, 1024 threads
// (16 waves -> 4 waves/SIMD). One neuron per thread. Layer-1 spikes
// are read (prefetched) from spk1; layers 2-4 via exact integer
// gathers over active (or complement) spike lists, 16 gather groups.
// ------------------------------------------------------------------
__global__ __launch_bounds__(1024, 1) void k_main(
    const uint8_t* __restrict__ k2T, const uint8_t* __restrict__ k3T,
    const uint8_t* __restrict__ k4T, const uint32_t* __restrict__ rs2,
    const uint32_t* __restrict__ rs3, const uint32_t* __restrict__ rs4,
    float* __restrict__ out)
{
  const int b = blockIdx.x;
  const int tid = threadIdx.x;
  const int lane = tid & 63;
  const int wave = tid >> 6;            // 16 gather groups

  __shared__ uint16_t list[1024];
  __shared__ uint4    pEa4[1024];       // [g][lane*4..+3] packed u16 sums (neurons 0,2 of quad)
  __shared__ uint4    pOa4[1024];       // neurons 1,3
  __shared__ uint4    wcnt4[4];
  __shared__ uint32_t lpos;
  uint32_t* pEa  = (uint32_t*)pEa4;
  uint32_t* pOa  = (uint32_t*)pOa4;
  uint32_t* wcnt = (uint32_t*)wcnt4;

  float m2 = 0.f, m3 = 0.f, m4 = 0.f;
  const uint32_t r2v = rs2[tid];
  const uint32_t r3v = rs3[tid];
  const uint32_t r4v = (tid < NOUT) ? rs4[tid] : 0u;

  auto sumcnt = [&]() -> uint32_t {
    uint4 a0 = wcnt4[0], a1 = wcnt4[1], a2 = wcnt4[2], a3 = wcnt4[3];
    return a0.x + a0.y + a0.z + a0.w + a1.x + a1.y + a1.z + a1.w +
           a2.x + a2.y + a2.z + a2.w + a3.x + a3.y + a3.z + a3.w;
  };

  auto writeList = [&](uint64_t cw) {
    uint32_t cnt = (uint32_t)__popcll(cw);
    uint32_t bs = 0;
    if (lane == 0) bs = atomicAdd(&lpos, cnt);
    bs = (uint32_t)__shfl((int)bs, 0);
    if ((cw >> lane) & 1ull)
      list[bs + (uint32_t)__popcll(cw & ((1ull << lane) - 1ull))] = (uint16_t)tid;
  };

  auto gatherBig = [&](const uint8_t* __restrict__ mat, uint32_t nLv) {
    uint32_t aE0=0,aE1=0,aE2=0,aE3=0,aO0=0,aO1=0,aO2=0,aO3=0;
    const uint8_t* bp = mat + (lane << 4);     // 64 lanes x 16B = full 1KB row
    uint32_t a = (uint32_t)wave;
    for (; a + 16 < nLv; a += 32) {            // 2 loads in flight
      uint32_t i0 = (uint32_t)__builtin_amdgcn_readfirstlane((int)list[a]);
      uint32_t i1 = (uint32_t)__builtin_amdgcn_readfirstlane((int)list[a + 16]);
      const uint4 w0 = *(const uint4*)(bp + ((size_t)i0 << 10));
      const uint4 w1 = *(const uint4*)(bp + ((size_t)i1 << 10));
      aE0 += w0.x & 0x00FF00FFu; aO0 += (w0.x >> 8) & 0x00FF00FFu;
      aE1 += w0.y & 0x00FF00FFu; aO1 += (w0.y >> 8) & 0x00FF00FFu;
      aE2 += w0.z & 0x00FF00FFu; aO2 += (w0.z >> 8) & 0x00FF00FFu;
      aE3 += w0.w & 0x00FF00FFu; aO3 += (w0.w >> 8) & 0x00FF00FFu;
      aE0 += w1.x & 0x00FF00FFu; aO0 += (w1.x >> 8) & 0x00FF00FFu;
      aE1 += w1.y & 0x00FF00FFu; aO1 += (w1.y >> 8) & 0x00FF00FFu;
      aE2 += w1.z & 0x00FF00FFu; aO2 += (w1.z >> 8) & 0x00FF00FFu;
      aE3 += w1.w & 0x00FF00FFu; aO3 += (w1.w >> 8) & 0x00FF00FFu;
    }
    if (a < nLv) {
      uint32_t i0 = (uint32_t)__builtin_amdgcn_readfirstlane((int)list[a]);
      const uint4 w0 = *(const uint4*)(bp + ((size_t)i0 << 10));
      aE0 += w0.x & 0x00FF00FFu; aO0 += (w0.x >> 8) & 0x00FF00FFu;
      aE1 += w0.y & 0x00FF00FFu; aO1 += (w0.y >> 8) & 0x00FF00FFu;
      aE2 += w0.z & 0x00FF00FFu; aO2 += (w0.z >> 8) & 0x00FF00FFu;
      aE3 += w0.w & 0x00FF00FFu; aO3 += (w0.w >> 8) & 0x00FF00FFu;
    }
    const int basei = (wave << 8) + (lane << 2);
    *(uint4*)&pEa[basei] = make_uint4(aE0, aE1, aE2, aE3);
    *(uint4*)&pOa[basei] = make_uint4(aO0, aO1, aO2, aO3);
  };

  auto gsum = [&](int jn) -> uint32_t {
    int w = jn >> 2, sh = (jn & 2) << 3;
    const uint32_t* P = (jn & 1) ? pOa : pEa;
    uint32_t s = 0;
    #pragma unroll
    for (int g = 0; g < 16; ++g) s += (P[(g << 8) + w] >> sh) & 0xffffu;
    return s;
  };

  float s1v = out[(size_t)b * NH + tid];       // prefetch spk1 row for t=0
  uint32_t nT, nL; bool cm;

  for (int t = 0; t < NT; ++t) {
    const size_t rowH = ((size_t)t * NB + b) * (size_t)NH;
    const size_t rowO = ((size_t)t * NB + b) * (size_t)NOUT;

    // ---- layer-1 spikes (precomputed by k_spk1); prefetch next row ----
    bool sA = s1v > 0.5f;
    {
      int tn = (t + 1 < NT) ? (t + 1) : t;
      s1v = out[((size_t)tn * NB + b) * (size_t)NH + tid];
    }
    uint64_t b1 = __ballot(sA);
    if (tid == 0) lpos = 0;
    if (lane == 0) wcnt[wave] = (uint32_t)__popcll(b1);
    __syncthreads();                                         // A
    nT = sumcnt(); cm = nT > 512; nL = cm ? 1024u - nT : nT;
    writeList(cm ? ~b1 : b1);
    __syncthreads();                                         // B
    const uint32_t n1 = nT, nl1 = nL; const bool cm1 = cm;
    if (nl1) gatherBig(k2T, nl1);
    __syncthreads();                                         // C

    // ---- layer 2 ----
    bool sp;
    {
      uint32_t gsv = nl1 ? gsum(tid) : 0u;
      uint32_t K = cm1 ? (r2v - gsv) : gsv;
      float cur = fmaf(S2C, (float)K, 0.001f * (float)n1);
      float rst = m2 > 1.0f ? 1.0f : 0.0f;
      m2 = fmaf(0.85f, m2, cur) - rst;
      sp = (m2 - 1.0f) > 0.0f;
      out[O_SPK2 + rowH + tid] = sp ? 1.0f : 0.0f;
    }
    uint64_t b2 = __ballot(sp);
    if (tid == 0) lpos = 0;
    if (lane == 0) wcnt[wave] = (uint32_t)__popcll(b2);
    __syncthreads();                                         // D
    nT = sumcnt(); cm = nT > 512; nL = cm ? 1024u - nT : nT;
    writeList(cm ? ~b2 : b2);
    __syncthreads();                                         // E
    const uint32_t n2 = nT, nl2 = nL; const bool cm2 = cm;
    if (nl2) gatherBig(k3T, nl2);
    __syncthreads();                                         // F

    // ---- layer 3 ----
    {
      uint32_t gsv = nl2 ? gsum(tid) : 0u;
      uint32_t K = cm2 ? (r3v - gsv) : gsv;
      float cur = fmaf(S2C, (float)K, 0.001f * (float)n2);
      float rst = m3 > 1.0f ? 1.0f : 0.0f;
      m3 = fmaf(0.8f, m3, cur) - rst;
      sp = (m3 - 1.0f) > 0.0f;
      out[O_SPK3 + rowH + tid] = sp ? 1.0f : 0.0f;
    }
    uint64_t b3 = __ballot(sp);
    if (tid == 0) lpos = 0;
    if (lane == 0) wcnt[wave] = (uint32_t)__popcll(b3);
    __syncthreads();                                         // G
    nT = sumcnt(); cm = nT > 512; nL = cm ? 1024u - nT : nT;
    writeList(cm ? ~b3 : b3);
    __syncthreads();                                         // H
    const uint32_t n3 = nT, nl3 = nL; const bool cm3 = cm;

    // ---- layer 4 gather (48-B padded rows; lanes 0..2 of each group) ----
    if (nl3 && lane < 3) {
      uint32_t aE0=0,aE1=0,aE2=0,aE3=0,aO0=0,aO1=0,aO2=0,aO3=0;
      const uint8_t* bp = k4T + (lane << 4);
      for (uint32_t a = (uint32_t)wave; a < nl3; a += 16) {
        uint32_t i0 = (uint32_t)__builtin_amdgcn_readfirstlane((int)list[a]);
        const uint4 w0 = *(const uint4*)(bp + (size_t)i0 * 48u);
        aE0 += w0.x & 0x00FF00FFu; aO0 += (w0.x >> 8) & 0x00FF00FFu;
        aE1 += w0.y & 0x00FF00FFu; aO1 += (w0.y >> 8) & 0x00FF00FFu;
        aE2 += w0.z & 0x00FF00FFu; aO2 += (w0.z >> 8) & 0x00FF00FFu;
        aE3 += w0.w & 0x00FF00FFu; aO3 += (w0.w >> 8) & 0x00FF00FFu;
      }
      const int basei = (wave << 8) + (lane << 2);
      *(uint4*)&pEa[basei] = make_uint4(aE0, aE1, aE2, aE3);
      *(uint4*)&pOa[basei] = make_uint4(aO0, aO1, aO2, aO3);
    }
    __syncthreads();                                         // I

    // ---- layer 4 membrane (reset-to-zero) ----
    if (tid < NOUT) {
      uint32_t gsv = nl3 ? gsum(tid) : 0u;
      uint32_t K = cm3 ? (r4v - gsv) : gsv;
      float cur = fmaf(S2C, (float)K, 0.001f * (float)n3);
      float rst = m4 > 1.0f ? 1.0f : 0.0f;
      float bsv = fmaf(0.95f, m4, cur);
      m4 = (rst > 0.0f) ? 0.0f : bsv;
      out[O_SPK4 + rowO + tid] = ((m4 - 1.0f) > 0.0f) ? 1.0f : 0.0f;
      out[O_MEM4 + rowO + tid] = m4;
    }
  }
}

extern "C" void kernel_launch(void* const* d_in, const int* in_sizes, int n_in,
                              void* d_out, int out_size, void* d_ws, size_t ws_size,
                              hipStream_t stream)
{
  const float* x  = (const float*)d_in[0];
  const float* w1 = (const float*)d_in[1];
  const float* w2 = (const float*)d_in[2];
  const float* w3 = (const float*)d_in[3];
  const float* w4 = (const float*)d_in[4];
  float* out = (float*)d_out;
  uint8_t* ws = (uint8_t*)d_ws;
  hipLaunchKernelGGL(k_prep,   dim3(21696), dim3(256), 0, stream, x, w1, w2, w3, w4, ws);
  hipLaunchKernelGGL(k_rowsum, dim3(2083),  dim3(256), 0, stream, w2, w3, w4, ws);
  hipLaunchKernelGGL(k_spk1,   dim3(256),   dim3(1024), 0, stream,
                     (const float*)(ws + WS_XT), (const float*)(ws + WS_Q1T), out);
  hipLaunchKernelGGL(k_main,   dim3(256),   dim3(1024), 0, stream,
                     ws + WS_K2T, ws + WS_K3T, ws + WS_K4T,
                     (const uint32_t*)(ws + WS_RS2), (const uint32_t*)(ws + WS_RS3),
                     (const uint32_t*)(ws + WS_RS4), out);
}

// Round 2
// 701.073 us; speedup vs baseline: 1.2595x; 1.2595x over previous
//
#include <hip/hip_runtime.h>
#include <stdint.h>

// Problem dims
#define NB  256
#define NT  100
#define NIN 128
#define NH  1024
#define NOUT 35

// d_out float offsets
#define O_SPK2 26214400ull
#define O_SPK3 52428800ull
#define O_SPK4 78643200ull
#define O_MEM4 79539200ull

// d_ws byte offsets (unchanged layout)
#define WS_XT   0ull          // 25600*128*4 = 13107200
#define WS_Q1T  13107200ull   // 128*1024*4  = 524288
#define WS_K2T  13631488ull   // 1048576
#define WS_K3T  14680064ull   // 1048576
#define WS_K4T  15728640ull   // 1024*48 = 49152 (padded stride 48)
#define WS_RS2  15777792ull   // 4096
#define WS_RS3  15781888ull   // 4096
#define WS_RS4  15785984ull   // 140

// scale = (w_max - w_min)/15 computed in python fp64 then cast to fp32
#define S2C ((float)((1.0 - 0.001) / 15.0))
#define S1C ((float)(1.0 / 15.0))

// ------------------------------------------------------------------
// K1: quantize weights -> transposed i8 index matrices + q1T fp32 + xt
// ------------------------------------------------------------------
__global__ void k_prep(const float* __restrict__ x, const float* __restrict__ w1,
                       const float* __restrict__ w2, const float* __restrict__ w3,
                       const float* __restrict__ w4, uint8_t* __restrict__ ws)
{
  long long id = (long long)blockIdx.x * 256 + threadIdx.x;
  if (id < 1048576) {                       // k2T[i*1024+j] = k(w2[j][i])
    int i = (int)(id >> 10), j = (int)(id & 1023);
    float wv = w2[(size_t)j * 1024 + i];
    float wc = fminf(fmaxf(wv, 0.001f), 1.0f);
    ws[WS_K2T + id] = (uint8_t)(int)rintf((wc - 0.001f) / S2C);
    return;
  }
  id -= 1048576;
  if (id < 1048576) {                       // k3T
    int i = (int)(id >> 10), j = (int)(id & 1023);
    float wv = w3[(size_t)j * 1024 + i];
    float wc = fminf(fmaxf(wv, 0.001f), 1.0f);
    ws[WS_K3T + id] = (uint8_t)(int)rintf((wc - 0.001f) / S2C);
    return;
  }
  id -= 1048576;
  if (id < 49152) {                         // k4T stride 48, pad j>=35 with 0
    int i = (int)(id / 48), j = (int)(id % 48);
    uint8_t v = 0;
    if (j < NOUT) {
      float wv = w4[(size_t)j * 1024 + i];
      float wc = fminf(fmaxf(wv, 0.001f), 1.0f);
      v = (uint8_t)(int)rintf((wc - 0.001f) / S2C);
    }
    ws[WS_K4T + id] = v;
    return;
  }
  id -= 49152;
  if (id < 131072) {                        // q1T[i*1024+j] = fake_quant(w1[j][i]) fp32
    int i = (int)(id >> 10), j = (int)(id & 1023);
    float wv = w1[(size_t)j * 128 + i];
    float wc = fminf(fmaxf(wv, -0.5f), 0.5f);
    float q = rintf((wc + 0.5f) / S1C) * S1C - 0.5f;
    ((float*)(ws + WS_Q1T))[id] = q;
    return;
  }
  id -= 131072;
  if (id < 3276800) {                       // xt[(t*256+b)*128+i] = x[b][t][i]/15
    int row = (int)(id >> 7), i = (int)(id & 127);
    int tt = row >> 8, bb = row & 255;
    ((float*)(ws + WS_XT))[id] = x[((size_t)bb * NT + tt) * NIN + i] / 15.0f;
  }
}

// ------------------------------------------------------------------
// K2: integer row-sums of k-indices (for complement-mode gathers)
// ------------------------------------------------------------------
__global__ void k_rowsum(const float* __restrict__ w2, const float* __restrict__ w3,
                         const float* __restrict__ w4, uint8_t* __restrict__ ws)
{
  int bid = blockIdx.x, tid = threadIdx.x;
  const float* W;
  uint32_t* o;
  if (bid < 1024)      { W = w2 + (size_t)bid * 1024;          o = (uint32_t*)(ws + WS_RS2) + bid; }
  else if (bid < 2048) { W = w3 + (size_t)(bid - 1024) * 1024; o = (uint32_t*)(ws + WS_RS3) + (bid - 1024); }
  else                 { W = w4 + (size_t)(bid - 2048) * 1024; o = (uint32_t*)(ws + WS_RS4) + (bid - 2048); }
  uint32_t s = 0;
  for (int i = tid; i < 1024; i += 256) {
    float wc = fminf(fmaxf(W[i], 0.001f), 1.0f);
    s += (uint32_t)(int)rintf((wc - 0.001f) / S2C);
  }
  #pragma unroll
  for (int off = 32; off; off >>= 1) s += (uint32_t)__shfl_down((int)s, off);
  __shared__ uint32_t red[4];
  if ((tid & 63) == 0) red[tid >> 6] = s;
  __syncthreads();
  if (tid == 0) *o = red[0] + red[1] + red[2] + red[3];
}

// ------------------------------------------------------------------
// K3 (v2): fused layer-1 GEMM + LIF scan, LDS-staged x.
// One block per batch elem, 512 threads, each handles neurons j=tid
// and j=tid+512. Per 25-t chunk: x chunk (25x128 fp32 = 12.8 KB)
// staged cooperatively into LDS once (coalesced float4), then read
// back with uniform-address ds_read_b128 (broadcast). FMA chain is
// ascending-i per (t,j), bitwise identical to the reference order.
// ------------------------------------------------------------------
__global__ __launch_bounds__(512, 1) void k_spk1(const float* __restrict__ xt,
                                                 const float* __restrict__ q1T,
                                                 float* __restrict__ out)
{
  __shared__ float xs[25 * 128];        // [tt][i], 12.8 KB
  const int b = blockIdx.x;
  const int tid = threadIdx.x;          // 0..511
  float m1a = 0.f, m1b = 0.f;

  for (int c = 0; c < 4; ++c) {
    __syncthreads();                    // xs reuse guard
    // stage chunk: 800 float4 (25 rows x 32 quads)
    {
      int e = tid;                      // first 512
      int tt = e >> 5, iq = e & 31;
      ((float4*)xs)[e] = *(const float4*)(xt + ((size_t)(c * 25 + tt) * NB + b) * NIN + iq * 4);
      e = tid + 512;                    // remaining 288
      if (e < 800) {
        tt = e >> 5; iq = e & 31;
        ((float4*)xs)[e] = *(const float4*)(xt + ((size_t)(c * 25 + tt) * NB + b) * NIN + iq * 4);
      }
    }
    __syncthreads();

    float acc0[25], acc1[25];
    #pragma unroll
    for (int tt = 0; tt < 25; ++tt) { acc0[tt] = 0.f; acc1[tt] = 0.f; }

    for (int ib = 0; ib < 16; ++ib) {   // rolled: keeps I$ small
      float q0[8], q1v[8];
      #pragma unroll
      for (int u = 0; u < 8; ++u) {
        q0[u]  = q1T[(size_t)(ib * 8 + u) * NH + tid];
        q1v[u] = q1T[(size_t)(ib * 8 + u) * NH + tid + 512];
      }
      #pragma unroll
      for (int tt = 0; tt < 25; ++tt) {
        const float4 xa = *(const float4*)&xs[tt * 128 + ib * 8];
        const float4 xb = *(const float4*)&xs[tt * 128 + ib * 8 + 4];
        acc0[tt] = fmaf(xa.x, q0[0], acc0[tt]);
        acc0[tt] = fmaf(xa.y, q0[1], acc0[tt]);
        acc0[tt] = fmaf(xa.z, q0[2], acc0[tt]);
        acc0[tt] = fmaf(xa.w, q0[3], acc0[tt]);
        acc0[tt] = fmaf(xb.x, q0[4], acc0[tt]);
        acc0[tt] = fmaf(xb.y, q0[5], acc0[tt]);
        acc0[tt] = fmaf(xb.z, q0[6], acc0[tt]);
        acc0[tt] = fmaf(xb.w, q0[7], acc0[tt]);
        acc1[tt] = fmaf(xa.x, q1v[0], acc1[tt]);
        acc1[tt] = fmaf(xa.y, q1v[1], acc1[tt]);
        acc1[tt] = fmaf(xa.z, q1v[2], acc1[tt]);
        acc1[tt] = fmaf(xa.w, q1v[3], acc1[tt]);
        acc1[tt] = fmaf(xb.x, q1v[4], acc1[tt]);
        acc1[tt] = fmaf(xb.y, q1v[5], acc1[tt]);
        acc1[tt] = fmaf(xb.z, q1v[6], acc1[tt]);
        acc1[tt] = fmaf(xb.w, q1v[7], acc1[tt]);
      }
    }
    // sequential LIF scan (subtract-reset), identical math/order
    #pragma unroll
    for (int tt = 0; tt < 25; ++tt) {
      const int t = c * 25 + tt;
      const size_t row = ((size_t)t * NB + b) * (size_t)NH;
      float rst0 = m1a > 1.0f ? 1.0f : 0.0f;
      m1a = fmaf(0.9f, m1a, acc0[tt]) - rst0;
      out[row + tid] = ((m1a - 1.0f) > 0.0f) ? 1.0f : 0.0f;
      float rst1 = m1b > 1.0f ? 1.0f : 0.0f;
      m1b = fmaf(0.9f, m1b, acc1[tt]) - rst1;
      out[row + tid + 512] = ((m1b - 1.0f) > 0.0f) ? 1.0f : 0.0f;
    }
  }
}

// ------------------------------------------------------------------
// K4: persistent per-batch-element SNN loop, 1024 threads
// (16 waves -> 4 waves/SIMD). One neuron per thread. Layer-1 spikes
// are read (prefetched) from spk1; layers 2-4 via exact integer
// gathers over active (or complement) spike lists, 16 gather groups.
// ------------------------------------------------------------------
__global__ __launch_bounds__(1024, 1) void k_main(
    const uint8_t* __restrict__ k2T, const uint8_t* __restrict__ k3T,
    const uint8_t* __restrict__ k4T, const uint32_t* __restrict__ rs2,
    const uint32_t* __restrict__ rs3, const uint32_t* __restrict__ rs4,
    float* __restrict__ out)
{
  const int b = blockIdx.x;
  const int tid = threadIdx.x;
  const int lane = tid & 63;
  const int wave = tid >> 6;            // 16 gather groups

  __shared__ uint16_t list[1024];
  __shared__ uint4    pEa4[1024];       // [g][lane*4..+3] packed u16 sums (neurons 0,2 of quad)
  __shared__ uint4    pOa4[1024];       // neurons 1,3
  __shared__ uint4    wcnt4[4];
  __shared__ uint32_t lpos;
  uint32_t* pEa  = (uint32_t*)pEa4;
  uint32_t* pOa  = (uint32_t*)pOa4;
  uint32_t* wcnt = (uint32_t*)wcnt4;

  float m2 = 0.f, m3 = 0.f, m4 = 0.f;
  const uint32_t r2v = rs2[tid];
  const uint32_t r3v = rs3[tid];
  const uint32_t r4v = (tid < NOUT) ? rs4[tid] : 0u;

  auto sumcnt = [&]() -> uint32_t {
    uint4 a0 = wcnt4[0], a1 = wcnt4[1], a2 = wcnt4[2], a3 = wcnt4[3];
    return a0.x + a0.y + a0.z + a0.w + a1.x + a1.y + a1.z + a1.w +
           a2.x + a2.y + a2.z + a2.w + a3.x + a3.y + a3.z + a3.w;
  };

  auto writeList = [&](uint64_t cw) {
    uint32_t cnt = (uint32_t)__popcll(cw);
    uint32_t bs = 0;
    if (lane == 0) bs = atomicAdd(&lpos, cnt);
    bs = (uint32_t)__shfl((int)bs, 0);
    if ((cw >> lane) & 1ull)
      list[bs + (uint32_t)__popcll(cw & ((1ull << lane) - 1ull))] = (uint16_t)tid;
  };

  auto gatherBig = [&](const uint8_t* __restrict__ mat, uint32_t nLv) {
    uint32_t aE0=0,aE1=0,aE2=0,aE3=0,aO0=0,aO1=0,aO2=0,aO3=0;
    const uint8_t* bp = mat + (lane << 4);     // 64 lanes x 16B = full 1KB row
    uint32_t a = (uint32_t)wave;
    for (; a + 16 < nLv; a += 32) {            // 2 loads in flight
      uint32_t i0 = (uint32_t)__builtin_amdgcn_readfirstlane((int)list[a]);
      uint32_t i1 = (uint32_t)__builtin_amdgcn_readfirstlane((int)list[a + 16]);
      const uint4 w0 = *(const uint4*)(bp + ((size_t)i0 << 10));
      const uint4 w1 = *(const uint4*)(bp + ((size_t)i1 << 10));
      aE0 += w0.x & 0x00FF00FFu; aO0 += (w0.x >> 8) & 0x00FF00FFu;
      aE1 += w0.y & 0x00FF00FFu; aO1 += (w0.y >> 8) & 0x00FF00FFu;
      aE2 += w0.z & 0x00FF00FFu; aO2 += (w0.z >> 8) & 0x00FF00FFu;
      aE3 += w0.w & 0x00FF00FFu; aO3 += (w0.w >> 8) & 0x00FF00FFu;
      aE0 += w1.x & 0x00FF00FFu; aO0 += (w1.x >> 8) & 0x00FF00FFu;
      aE1 += w1.y & 0x00FF00FFu; aO1 += (w1.y >> 8) & 0x00FF00FFu;
      aE2 += w1.z & 0x00FF00FFu; aO2 += (w1.z >> 8) & 0x00FF00FFu;
      aE3 += w1.w & 0x00FF00FFu; aO3 += (w1.w >> 8) & 0x00FF00FFu;
    }
    if (a < nLv) {
      uint32_t i0 = (uint32_t)__builtin_amdgcn_readfirstlane((int)list[a]);
      const uint4 w0 = *(const uint4*)(bp + ((size_t)i0 << 10));
      aE0 += w0.x & 0x00FF00FFu; aO0 += (w0.x >> 8) & 0x00FF00FFu;
      aE1 += w0.y & 0x00FF00FFu; aO1 += (w0.y >> 8) & 0x00FF00FFu;
      aE2 += w0.z & 0x00FF00FFu; aO2 += (w0.z >> 8) & 0x00FF00FFu;
      aE3 += w0.w & 0x00FF00FFu; aO3 += (w0.w >> 8) & 0x00FF00FFu;
    }
    const int basei = (wave << 8) + (lane << 2);
    *(uint4*)&pEa[basei] = make_uint4(aE0, aE1, aE2, aE3);
    *(uint4*)&pOa[basei] = make_uint4(aO0, aO1, aO2, aO3);
  };

  auto gsum = [&](int jn) -> uint32_t {
    int w = jn >> 2, sh = (jn & 2) << 3;
    const uint32_t* P = (jn & 1) ? pOa : pEa;
    uint32_t s = 0;
    #pragma unroll
    for (int g = 0; g < 16; ++g) s += (P[(g << 8) + w] >> sh) & 0xffffu;
    return s;
  };

  float s1v = out[(size_t)b * NH + tid];       // prefetch spk1 row for t=0
  uint32_t nT, nL; bool cm;

  for (int t = 0; t < NT; ++t) {
    const size_t rowH = ((size_t)t * NB + b) * (size_t)NH;
    const size_t rowO = ((size_t)t * NB + b) * (size_t)NOUT;

    // ---- layer-1 spikes (precomputed by k_spk1); prefetch next row ----
    bool sA = s1v > 0.5f;
    {
      int tn = (t + 1 < NT) ? (t + 1) : t;
      s1v = out[((size_t)tn * NB + b) * (size_t)NH + tid];
    }
    uint64_t b1 = __ballot(sA);
    if (tid == 0) lpos = 0;
    if (lane == 0) wcnt[wave] = (uint32_t)__popcll(b1);
    __syncthreads();                                         // A
    nT = sumcnt(); cm = nT > 512; nL = cm ? 1024u - nT : nT;
    writeList(cm ? ~b1 : b1);
    __syncthreads();                                         // B
    const uint32_t n1 = nT, nl1 = nL; const bool cm1 = cm;
    if (nl1) gatherBig(k2T, nl1);
    __syncthreads();                                         // C

    // ---- layer 2 ----
    bool sp;
    {
      uint32_t gsv = nl1 ? gsum(tid) : 0u;
      uint32_t K = cm1 ? (r2v - gsv) : gsv;
      float cur = fmaf(S2C, (float)K, 0.001f * (float)n1);
      float rst = m2 > 1.0f ? 1.0f : 0.0f;
      m2 = fmaf(0.85f, m2, cur) - rst;
      sp = (m2 - 1.0f) > 0.0f;
      out[O_SPK2 + rowH + tid] = sp ? 1.0f : 0.0f;
    }
    uint64_t b2 = __ballot(sp);
    if (tid == 0) lpos = 0;
    if (lane == 0) wcnt[wave] = (uint32_t)__popcll(b2);
    __syncthreads();                                         // D
    nT = sumcnt(); cm = nT > 512; nL = cm ? 1024u - nT : nT;
    writeList(cm ? ~b2 : b2);
    __syncthreads();                                         // E
    const uint32_t n2 = nT, nl2 = nL; const bool cm2 = cm;
    if (nl2) gatherBig(k3T, nl2);
    __syncthreads();                                         // F

    // ---- layer 3 ----
    {
      uint32_t gsv = nl2 ? gsum(tid) : 0u;
      uint32_t K = cm2 ? (r3v - gsv) : gsv;
      float cur = fmaf(S2C, (float)K, 0.001f * (float)n2);
      float rst = m3 > 1.0f ? 1.0f : 0.0f;
      m3 = fmaf(0.8f, m3, cur) - rst;
      sp = (m3 - 1.0f) > 0.0f;
      out[O_SPK3 + rowH + tid] = sp ? 1.0f : 0.0f;
    }
    uint64_t b3 = __ballot(sp);
    if (tid == 0) lpos = 0;
    if (lane == 0) wcnt[wave] = (uint32_t)__popcll(b3);
    __syncthreads();                                         // G
    nT = sumcnt(); cm = nT > 512; nL = cm ? 1024u - nT : nT;
    writeList(cm ? ~b3 : b3);
    __syncthreads();                                         // H
    const uint32_t n3 = nT, nl3 = nL; const bool cm3 = cm;

    // ---- layer 4 gather (48-B padded rows; lanes 0..2 of each group) ----
    if (nl3 && lane < 3) {
      uint32_t aE0=0,aE1=0,aE2=0,aE3=0,aO0=0,aO1=0,aO2=0,aO3=0;
      const uint8_t* bp = k4T + (lane << 4);
      for (uint32_t a = (uint32_t)wave; a < nl3; a += 16) {
        uint32_t i0 = (uint32_t)__builtin_amdgcn_readfirstlane((int)list[a]);
        const uint4 w0 = *(const uint4*)(bp + (size_t)i0 * 48u);
        aE0 += w0.x & 0x00FF00FFu; aO0 += (w0.x >> 8) & 0x00FF00FFu;
        aE1 += w0.y & 0x00FF00FFu; aO1 += (w0.y >> 8) & 0x00FF00FFu;
        aE2 += w0.z & 0x00FF00FFu; aO2 += (w0.z >> 8) & 0x00FF00FFu;
        aE3 += w0.w & 0x00FF00FFu; aO3 += (w0.w >> 8) & 0x00FF00FFu;
      }
      const int basei = (wave << 8) + (lane << 2);
      *(uint4*)&pEa[basei] = make_uint4(aE0, aE1, aE2, aE3);
      *(uint4*)&pOa[basei] = make_uint4(aO0, aO1, aO2, aO3);
    }
    __syncthreads();                                         // I

    // ---- layer 4 membrane (reset-to-zero) ----
    if (tid < NOUT) {
      uint32_t gsv = nl3 ? gsum(tid) : 0u;
      uint32_t K = cm3 ? (r4v - gsv) : gsv;
      float cur = fmaf(S2C, (float)K, 0.001f * (float)n3);
      float rst = m4 > 1.0f ? 1.0f : 0.0f;
      float bsv = fmaf(0.95f, m4, cur);
      m4 = (rst > 0.0f) ? 0.0f : bsv;
      out[O_SPK4 + rowO + tid] = ((m4 - 1.0f) > 0.0f) ? 1.0f : 0.0f;
      out[O_MEM4 + rowO + tid] = m4;
    }
  }
}

extern "C" void kernel_launch(void* const* d_in, const int* in_sizes, int n_in,
                              void* d_out, int out_size, void* d_ws, size_t ws_size,
                              hipStream_t stream)
{
  const float* x  = (const float*)d_in[0];
  const float* w1 = (const float*)d_in[1];
  const float* w2 = (const float*)d_in[2];
  const float* w3 = (const float*)d_in[3];
  const float* w4 = (const float*)d_in[4];
  float* out = (float*)d_out;
  uint8_t* ws = (uint8_t*)d_ws;
  hipLaunchKernelGGL(k_prep,   dim3(21696), dim3(256), 0, stream, x, w1, w2, w3, w4, ws);
  hipLaunchKernelGGL(k_rowsum, dim3(2083),  dim3(256), 0, stream, w2, w3, w4, ws);
  hipLaunchKernelGGL(k_spk1,   dim3(256),   dim3(512), 0, stream,
                     (const float*)(ws + WS_XT), (const float*)(ws + WS_Q1T), out);
  hipLaunchKernelGGL(k_main,   dim3(256),   dim3(1024), 0, stream,
                     ws + WS_K2T, ws + WS_K3T, ws + WS_K4T,
                     (const uint32_t*)(ws + WS_RS2), (const uint32_t*)(ws + WS_RS3),
                     (const uint32_t*)(ws + WS_RS4), out);
}